// Round 6
// baseline (77.064 us; speedup 1.0000x reference)
//
#include <hip/hip_runtime.h>

#define Bc 8
#define Nc 360
#define Dc 128

typedef float f32x4 __attribute__((ext_vector_type(4)));

// proj: Bv[row,c] = w2_c * ( emb[row,:] . W1[c, 0:128] )              (sender,  j side)
//       Av[row,c] = w2_c * ( emb[row,:] . W1[c, 128:256] + b1[c] )    (receiver, i side)
// rsA/rsB[row] accumulate row sums (atomic; buffer memset to 0 on stream).
// Block 256 = 4 waves. Wave: 64 rows (lane) x 8 cols (per-wave col group).
// No LDS, no barriers: emb read per-lane (L1 line reuse via unroll-4),
// W1 read at wave-uniform addresses kept in the VMEM path (no readfirstlane).
__global__ __launch_bounds__(256) void proj_kernel(
    const float* __restrict__ emb, const float* __restrict__ W1,
    const float* __restrict__ b1, const float* __restrict__ W2,
    float* __restrict__ Av, float* __restrict__ Bv,
    float* __restrict__ rsA, float* __restrict__ rsB)
{
    const int t    = threadIdx.x;
    const int lane = t & 63;
    const int w    = t >> 6;                    // intentionally NOT readfirstlane'd
    const int row  = blockIdx.x * 64 + lane;    // 2880 = 45*64, exact
    const int c0   = blockIdx.y * 32 + w * 8;   // 256 = 8*32, exact
    const bool recv = (c0 >= Dc);
    const int  cl   = recv ? (c0 - Dc) : c0;

    const float* wbase = W1 + cl * (2 * Dc) + (recv ? Dc : 0);
    const float* ebase = emb + row * Dc;

    float acc[8];
    #pragma unroll
    for (int cc = 0; cc < 8; ++cc) acc[cc] = 0.0f;

    #pragma unroll 4
    for (int k4 = 0; k4 < 32; ++k4) {
        const f32x4 ev = *(const f32x4*)(ebase + k4 * 4);          // per-lane
        #pragma unroll
        for (int cc = 0; cc < 8; ++cc) {
            const f32x4 wv = *(const f32x4*)(wbase + cc * (2 * Dc) + k4 * 4); // uniform
            acc[cc] = fmaf(wv[0], ev[0], acc[cc]);
            acc[cc] = fmaf(wv[1], ev[1], acc[cc]);
            acc[cc] = fmaf(wv[2], ev[2], acc[cc]);
            acc[cc] = fmaf(wv[3], ev[3], acc[cc]);
        }
    }

    #pragma unroll
    for (int cc = 0; cc < 8; ++cc) {
        float v = recv ? (acc[cc] + b1[cl + cc]) : acc[cc];
        acc[cc] = v * W2[cl + cc];
    }
    float* dst = (recv ? Av : Bv) + row * Dc + cl;
    *(float4*)(dst + 0) = make_float4(acc[0], acc[1], acc[2], acc[3]);
    *(float4*)(dst + 4) = make_float4(acc[4], acc[5], acc[6], acc[7]);

    const float sum8 = ((acc[0] + acc[1]) + (acc[2] + acc[3]))
                     + ((acc[4] + acc[5]) + (acc[6] + acc[7]));
    atomicAdd((recv ? rsA : rsB) + row, sum8);
}

// edge: out[b,i,j] = relu( b2 + 0.5*(rsA[i]+rsB[j]) + sum_d s_d*|Av[i,d]+Bv[j,d]| ),
//       s_d = 0.5*sgn(w2_d) computed in-loop from W2 (uniform load, copysign).
// Block 256 = 4 waves. Wave: 64 j (lane, per-lane B rows) x 8 i (uniform A rows).
// Grid (6, 12, 8) = 576 blocks. No LDS, no barriers, no asm.
__global__ __launch_bounds__(256) void edge_kernel(
    const float* __restrict__ Av, const float* __restrict__ Bv,
    const float* __restrict__ W2, const float* __restrict__ b2,
    const float* __restrict__ rsA, const float* __restrict__ rsB,
    float* __restrict__ out)
{
    const int t    = threadIdx.x;
    const int lane = t & 63;
    const int w    = t >> 6;                        // NOT readfirstlane'd (keep VMEM path)
    const int b    = blockIdx.z;
    const int j0   = blockIdx.x * 64;               // 6*64 = 384 covers 360 (mask tail)
    const int ia   = blockIdx.y * 32 + w * 8;       // 12*32 = 384 covers 360 (mask tail)
    const int iacl = (ia > Nc - 8) ? (Nc - 8) : ia; // clamped: 8 valid rows for loads

    const int jg = j0 + lane;
    const int jc = (jg > Nc - 1) ? (Nc - 1) : jg;

    const float* bbase = Bv + (b * Nc + jc) * Dc;     // per-lane row
    const float* abase = Av + (b * Nc + iacl) * Dc;   // wave-uniform rows

    float acc[8];
    #pragma unroll
    for (int q = 0; q < 8; ++q) acc[q] = 0.0f;

    #pragma unroll 4
    for (int k4 = 0; k4 < 32; ++k4) {
        const f32x4 bv  = *(const f32x4*)(bbase + k4 * 4);   // per-lane (L1 line reuse)
        const f32x4 w2v = *(const f32x4*)(W2 + k4 * 4);      // uniform
        f32x4 av[8];
        #pragma unroll
        for (int q = 0; q < 8; ++q)
            av[q] = *(const f32x4*)(abase + q * Dc + k4 * 4); // uniform
        #pragma unroll
        for (int e = 0; e < 4; ++e) {
            const float se = copysignf(0.5f, w2v[e]);
            const float be = bv[e];
            #pragma unroll
            for (int q = 0; q < 8; ++q) {
                const float tq = av[q][e] + be;
                acc[q] = fmaf(se, fabsf(tq), acc[q]);        // |.| = free VOP3 modifier
            }
        }
    }

    if (jg < Nc) {
        const float base = b2[0] + rsB[b * Nc + jc];   // rs* already include the 0.5 factor? no:
        // rsA/rsB hold full row sums; fold 0.5 here.
        #pragma unroll
        for (int q = 0; q < 8; ++q) {
            const int ig = ia + q;
            if (ig < Nc) {
                const float lin = fmaf(0.5f, rsA[b * Nc + iacl + q] + rsB[b * Nc + jc], acc[q]) + b2[0];
                out[(b * Nc + ig) * Nc + jg] = fmaxf(lin, 0.0f);
            }
        }
    }
}

extern "C" void kernel_launch(void* const* d_in, const int* in_sizes, int n_in,
                              void* d_out, int out_size, void* d_ws, size_t ws_size,
                              hipStream_t stream) {
    const float* emb = (const float*)d_in[0];   // [B,N,D]
    const float* W1  = (const float*)d_in[1];   // [D, 2D]
    const float* b1  = (const float*)d_in[2];   // [D]
    const float* W2  = (const float*)d_in[3];   // [1, D]
    const float* b2  = (const float*)d_in[4];   // [1]
    float* out = (float*)d_out;                 // [B,N,N,1]

    float* Av  = (float*)d_ws;                  // [2880,128] w2-scaled receiver proj (+b1)
    float* Bv  = Av + Bc * Nc * Dc;             // [2880,128] w2-scaled sender proj
    float* rsA = Bv + Bc * Nc * Dc;             // [2880] row sums of Av
    float* rsB = rsA + Bc * Nc;                 // [2880] row sums of Bv

    hipMemsetAsync(rsA, 0, 2 * Bc * Nc * sizeof(float), stream);
    proj_kernel<<<dim3(45, 8), 256, 0, stream>>>(emb, W1, b1, W2, Av, Bv, rsA, rsB);
    edge_kernel<<<dim3(6, 12, Bc), 256, 0, stream>>>(Av, Bv, W2, b2, rsA, rsB, out);
}

// Round 7
// 65.771 us; speedup vs baseline: 1.1717x; 1.1717x over previous
//
#include <hip/hip_runtime.h>

#define Bc 8
#define Nc 360
#define Dc 128

typedef float f32x4 __attribute__((ext_vector_type(4)));

// W1p[k4][c][e] = (c<128) ? W1[c][k4*4+e] : W1[c-128][128 + k4*4+e]
// One-time repack so proj's weight loads are coalesced. Grid 32 x 256 thr.
__global__ __launch_bounds__(256) void w1t_kernel(
    const float* __restrict__ W1, float* __restrict__ W1p)
{
    const int c  = threadIdx.x;            // 0..255
    const int k4 = blockIdx.x;             // 0..31
    const int row = (c < Dc) ? c : (c - Dc);
    const int off = (c < Dc) ? 0 : Dc;
    const f32x4 v = *(const f32x4*)(W1 + row * (2 * Dc) + off + k4 * 4);
    *(f32x4*)(W1p + (k4 * 256 + c) * 4) = v;
}

// proj (lane <-> output column c):
//   B-half (c<128):  Bt[b][c>>2][n][c&3] = w2_c * (emb[row,:] . W1[c,0:128])
//   A-half (c>=128): Av[row][c-128]      = w2_c * (emb[row,:] . W1[c-128,128:256] + b1[c-128])
//   rsA/rsB[row] += per-row sums (shfl-reduce + lane0 atomic; buffers memset to 0).
// Block = 1 wave (64 thr). Grid (180 row-groups of 16, 4 c-groups) = 720 blocks.
// Loads: W1p coalesced b128, emb uniform b128. No LDS, no barriers.
__global__ __launch_bounds__(64) void proj_kernel(
    const float* __restrict__ emb, const float* __restrict__ W1p,
    const float* __restrict__ b1, const float* __restrict__ W2,
    float* __restrict__ Av, float* __restrict__ Bt,
    float* __restrict__ rsA, float* __restrict__ rsB)
{
    const int lane = threadIdx.x;
    const int r0   = blockIdx.x * 16;        // row base, 0..2864
    const int cg   = blockIdx.y;             // 0..3 (0,1 = B-half; 2,3 = A-half)
    const int c    = cg * 64 + lane;         // 0..255
    const bool recv = (cg >= 2);             // uniform per wave
    const int  cl   = recv ? (c - Dc) : c;   // per-lane local col

    float acc[16];
    #pragma unroll
    for (int r = 0; r < 16; ++r) acc[r] = 0.0f;

    const float* wp = W1p + c * 4;           // + k4*1024 floats per iter (coalesced)
    const float* ep = emb + r0 * Dc;         // uniform rows

    #pragma unroll 4
    for (int k4 = 0; k4 < 32; ++k4) {
        const f32x4 wv = *(const f32x4*)(wp + k4 * 1024);
        #pragma unroll
        for (int r = 0; r < 16; ++r) {
            const f32x4 ev = *(const f32x4*)(ep + r * Dc + k4 * 4);   // uniform
            acc[r] = fmaf(wv[0], ev[0], acc[r]);
            acc[r] = fmaf(wv[1], ev[1], acc[r]);
            acc[r] = fmaf(wv[2], ev[2], acc[r]);
            acc[r] = fmaf(wv[3], ev[3], acc[r]);
        }
    }

    const float bb = recv ? b1[cl] : 0.0f;   // per-lane coalesced
    const float ww = W2[cl];
    #pragma unroll
    for (int r = 0; r < 16; ++r) acc[r] = (acc[r] + bb) * ww;

    // stores + row-sum reduce
    #pragma unroll
    for (int r = 0; r < 16; ++r) {
        const int gr = r0 + r;               // uniform
        const int gb = gr / Nc;
        const int n  = gr - gb * Nc;
        if (recv) {
            Av[gr * Dc + cl] = acc[r];                                  // coalesced
        } else {
            Bt[((gb * 32 + (c >> 2)) * Nc + n) * 4 + (c & 3)] = acc[r]; // 16B segments
        }
        float v = acc[r];
        #pragma unroll
        for (int m = 32; m >= 1; m >>= 1) v += __shfl_xor(v, m);
        if (lane == 0) atomicAdd((recv ? rsA : rsB) + gr, v);
    }
}

// edge: out[b,i,j] = relu( b2 + 0.5*(rsA[i]+rsB[j]) + sum_d s_d*|Av[i,d]+Bt[...,j,...]| )
// Block = 1 wave; lane <-> j (coalesced Bt b128 loads); 8 i-rows uniform.
// Grid (6, 45, 8) = 2160 blocks. No LDS, no barriers, no asm.
__global__ __launch_bounds__(64) void edge_kernel(
    const float* __restrict__ Av, const float* __restrict__ Bt,
    const float* __restrict__ W2, const float* __restrict__ b2,
    const float* __restrict__ rsA, const float* __restrict__ rsB,
    float* __restrict__ out)
{
    const int lane = threadIdx.x;
    const int b    = blockIdx.z;
    const int j0   = blockIdx.x * 64;           // 6*64 = 384 covers 360 (mask tail)
    const int ia   = blockIdx.y * 8;            // 45*8 = 360 exact
    const int jg   = j0 + lane;
    const int jc   = (jg > Nc - 1) ? (Nc - 1) : jg;

    const float* bp = Bt + (b * 32 * Nc + jc) * 4;   // + k4*Nc*4 per iter (coalesced b128)
    const float* ap = Av + (b * Nc + ia) * Dc;       // uniform

    float acc[8];
    #pragma unroll
    for (int q = 0; q < 8; ++q) acc[q] = 0.0f;

    #pragma unroll 4
    for (int k4 = 0; k4 < 32; ++k4) {
        const f32x4 bv  = *(const f32x4*)(bp + k4 * (Nc * 4));
        const f32x4 w2v = *(const f32x4*)(W2 + k4 * 4);        // uniform
        f32x4 av[8];
        #pragma unroll
        for (int q = 0; q < 8; ++q)
            av[q] = *(const f32x4*)(ap + q * Dc + k4 * 4);     // uniform
        #pragma unroll
        for (int e = 0; e < 4; ++e) {
            const float se = copysignf(0.5f, w2v[e]);
            const float be = bv[e];
            #pragma unroll
            for (int q = 0; q < 8; ++q) {
                const float tq = av[q][e] + be;
                acc[q] = fmaf(se, fabsf(tq), acc[q]);          // |.| = free modifier
            }
        }
    }

    if (jg < Nc) {
        const float sig = rsB[b * Nc + jc];                    // per-lane coalesced
        const float bb  = b2[0];
        #pragma unroll
        for (int q = 0; q < 8; ++q) {
            const float lin = fmaf(0.5f, rsA[b * Nc + ia + q] + sig, acc[q]) + bb;
            out[(b * Nc + ia + q) * Nc + jg] = fmaxf(lin, 0.0f);
        }
    }
}

extern "C" void kernel_launch(void* const* d_in, const int* in_sizes, int n_in,
                              void* d_out, int out_size, void* d_ws, size_t ws_size,
                              hipStream_t stream) {
    const float* emb = (const float*)d_in[0];   // [B,N,D]
    const float* W1  = (const float*)d_in[1];   // [D, 2D]
    const float* b1  = (const float*)d_in[2];   // [D]
    const float* W2  = (const float*)d_in[3];   // [1, D]
    const float* b2  = (const float*)d_in[4];   // [1]
    float* out = (float*)d_out;                 // [B,N,N,1]

    float* Av  = (float*)d_ws;                  // [2880,128] w2-scaled receiver proj (+b1)
    float* Bt  = Av + Bc * Nc * Dc;             // [8][32][360][4] packed sender proj
    float* W1p = Bt + Bc * Nc * Dc;             // [32][256][4] repacked W1
    float* rsA = W1p + 32 * 256 * 4;            // [2880]
    float* rsB = rsA + Bc * Nc;                 // [2880]

    hipMemsetAsync(rsA, 0, 2 * Bc * Nc * sizeof(float), stream);
    w1t_kernel<<<dim3(32), 256, 0, stream>>>(W1, W1p);
    proj_kernel<<<dim3(180, 4), 64, 0, stream>>>(emb, W1p, b1, W2, Av, Bt, rsA, rsB);
    edge_kernel<<<dim3(6, 45, Bc), 64, 0, stream>>>(Av, Bt, W2, b2, rsA, rsB, out);
}

// Round 8
// 57.064 us; speedup vs baseline: 1.3505x; 1.1526x over previous
//
#include <hip/hip_runtime.h>

#define Bc 8
#define Nc 360
#define Dc 128
#define NSLOT 132      // padded slots per side = 33 groups of 4
#define NG 33
#define NC2 264        // slots both sides (B-side first, then A-side)

typedef float f32x4 __attribute__((ext_vector_type(4)));

// ---------------- prep: permutation (positives of w2 first), gsplit ----------------
// 1 wave. pmap[s] = original d for slot s, or -1 (zero pad). gsplit: groups < gsplit add, >= subtract.
__global__ __launch_bounds__(64) void prep_kernel(
    const float* __restrict__ W2, int* __restrict__ pmap, int* __restrict__ gsplit)
{
    const int lane = threadIdx.x;
    // clear pads
    pmap[lane] = -1; pmap[64 + lane] = -1;
    if (lane < 4) pmap[128 + lane] = -1;

    const bool p0 = W2[lane] >= 0.0f;
    const bool p1 = W2[64 + lane] >= 0.0f;
    const unsigned long long m0 = __ballot(p0);
    const unsigned long long m1 = __ballot(p1);
    const unsigned long long below = (lane == 0) ? 0ull : (~0ull >> (64 - lane));
    const int cnt = __popcll(m0) + __popcll(m1);
    const int gs  = (cnt + 3) >> 2;
    if (lane == 0) *gsplit = gs;

    // positive slots: rank among positives
    const int pr0 = __popcll(m0 & below);
    const int pr1 = __popcll(m0) + __popcll(m1 & below);
    // negative slots: gs*4 + rank among negatives
    const int nr0 = __popcll(~m0 & below);
    const int nr1 = __popcll(~m0) + __popcll(~m1 & below);
    // ordered writes within one wave: pads first (above), then ranks — same wave, no race across slots
    __builtin_amdgcn_s_barrier();
    if (p0) pmap[pr0] = lane;            else pmap[gs * 4 + nr0] = lane;
    if (p1) pmap[pr1] = 64 + lane;       else pmap[gs * 4 + nr1] = 64 + lane;
}

// ---------------- fillw: packed, permuted, 0.5*w2-scaled W1 + b1p ----------------
// W1p[k4][c][e]: c<132 -> B-side slot (W1[pd][0:128]); c>=132 -> A-side slot (W1[pd][128:256]).
__global__ __launch_bounds__(256) void fillw_kernel(
    const float* __restrict__ W1, const float* __restrict__ W2, const float* __restrict__ b1,
    const int* __restrict__ pmap, float* __restrict__ W1p, float* __restrict__ b1p)
{
    const int k4 = blockIdx.x;                       // 0..31
    for (int c = threadIdx.x; c < NC2; c += 256) {
        const int side = (c >= NSLOT);               // 0 = B (sender), 1 = A (receiver)
        const int cm   = side ? c - NSLOT : c;
        const int pd   = pmap[cm];
        f32x4 v = {0.f, 0.f, 0.f, 0.f};
        if (pd >= 0) {
            const float sc = 0.5f * W2[pd];
            const float* src = W1 + pd * (2 * Dc) + side * Dc + k4 * 4;
            v[0] = sc * src[0]; v[1] = sc * src[1]; v[2] = sc * src[2]; v[3] = sc * src[3];
        }
        *(f32x4*)(W1p + (k4 * NC2 + c) * 4) = v;
        if (k4 == 0)
            b1p[c] = (side && pd >= 0) ? 0.5f * W2[pd] * b1[pd] : 0.0f;
    }
}

// ---------------- proj ----------------
// Avp[b*360+n][s] = A'-slot values; Btp[b][g][n][e] = B'-slot values; rs* = row sums (atomic).
// Wave: lane <-> slot column c (coalesced W1p loads); 8 rows via VMEM broadcast loads
// (base made formally divergent with mbcnt so the compiler keeps them in the pipelined global path).
__global__ __launch_bounds__(64) void proj_kernel(
    const float* __restrict__ emb, const float* __restrict__ W1p, const float* __restrict__ b1p,
    float* __restrict__ Avp, float* __restrict__ Btp,
    float* __restrict__ rsA, float* __restrict__ rsB)
{
    const int lane = threadIdx.x;
    const int r0   = blockIdx.x * 8;                 // 2880/8 = 360; 360%8==0 -> one batch per block
    const int cg   = blockIdx.y;                     // 0..4
    const int c    = cg * 64 + lane;                 // 0..319
    const int cc   = (c < NC2) ? c : (NC2 - 1);     // clamp for loads
    const int dz   = __builtin_amdgcn_mbcnt_lo(0u, 0u);  // == 0, divergent-typed

    float acc[8];
    const float binit = b1p[cc];
    #pragma unroll
    for (int r = 0; r < 8; ++r) acc[r] = binit;

    const float* wp = W1p + cc * 4;
    const float* ep = emb + (r0 + dz) * Dc;          // divergent base -> VMEM broadcast loads

    #pragma unroll 4
    for (int k4 = 0; k4 < 32; ++k4) {
        const f32x4 wv = *(const f32x4*)(wp + k4 * NC2 * 4);   // coalesced b128
        #pragma unroll
        for (int r = 0; r < 8; ++r) {
            const f32x4 ev = *(const f32x4*)(ep + r * Dc + k4 * 4);  // broadcast (1 line)
            acc[r] = fmaf(wv[0], ev[0], acc[r]);
            acc[r] = fmaf(wv[1], ev[1], acc[r]);
            acc[r] = fmaf(wv[2], ev[2], acc[r]);
            acc[r] = fmaf(wv[3], ev[3], acc[r]);
        }
    }

    const bool valid = (c < NC2);
    const int  side  = (c >= NSLOT);                 // per-lane
    const int  cm    = side ? c - NSLOT : c;
    const int  bidx  = r0 / Nc;                      // uniform
    const int  nb    = r0 - bidx * Nc;

    #pragma unroll
    for (int r = 0; r < 8; ++r) {
        const int n = nb + r;
        if (valid) {
            if (side) Avp[(bidx * Nc + n) * NSLOT + cm] = acc[r];                       // contiguous
            else      Btp[((bidx * NG + (cm >> 2)) * Nc + n) * 4 + (cm & 3)] = acc[r];  // 16B segs
        }
        float vA = (valid && side)  ? acc[r] : 0.0f;
        float vB = (valid && !side) ? acc[r] : 0.0f;
        #pragma unroll
        for (int m = 32; m >= 1; m >>= 1) { vA += __shfl_xor(vA, m); vB += __shfl_xor(vB, m); }
        if (lane == 0) {
            if (cg >= 2) atomicAdd(rsA + bidx * Nc + n, vA);
            if (cg <= 2) atomicAdd(rsB + bidx * Nc + n, vB);
        }
    }
}

// ---------------- edge ----------------
// out[b,i,j] = relu( b2 + rsA[i] + rsB[j] + sum_g sgn_g * sum_e |a[g,e] + b[j,g,e]| )
// Block = 4 waves; wave = 1 i-row x 192 j (3 per lane). Grid (90, 2, 8) = 1440 blocks.
// a-row in SGPRs (chunked preload, static indices); B per-lane coalesced b128 from Btp.
__global__ __launch_bounds__(256) void edge_kernel(
    const float* __restrict__ Avp, const float* __restrict__ Btp,
    const float* __restrict__ b2, const float* __restrict__ rsA,
    const float* __restrict__ rsB, const int* __restrict__ gsplit_p,
    float* __restrict__ out)
{
    const int t    = threadIdx.x;
    const int lane = t & 63;
    const int wid  = __builtin_amdgcn_readfirstlane(t >> 6);
    const int b    = blockIdx.z;
    const int i    = blockIdx.x * 4 + wid;           // uniform per wave
    const int j0   = blockIdx.y * 168;               // halves [0,192) and [168,360): overlap idempotent
    const int gsplit = *gsplit_p;                    // uniform

    const float* arow = Avp + (b * Nc + i) * NSLOT;  // uniform -> s_load
    const float* bp   = Btp + (b * NG * Nc + j0 + lane) * 4;   // per-lane; + g*Nc*4 per group

    float acc0 = 0.0f, acc1 = 0.0f, acc2 = 0.0f;

    #pragma unroll
    for (int ch = 0; ch < 3; ++ch) {
        float a_ch[44];
        #pragma unroll
        for (int s = 0; s < 44; ++s) a_ch[s] = arow[ch * 44 + s];   // uniform -> SGPRs
        #pragma unroll
        for (int g2 = 0; g2 < 11; ++g2) {
            const int g = ch * 11 + g2;
            const float sg = (g < gsplit) ? 1.0f : -1.0f;            // uniform select
            const f32x4 b0 = *(const f32x4*)(bp + (g * Nc +   0) * 4);
            const f32x4 b1v = *(const f32x4*)(bp + (g * Nc +  64) * 4);
            const f32x4 b2v = *(const f32x4*)(bp + (g * Nc + 128) * 4);
            #pragma unroll
            for (int e = 0; e < 4; ++e) {
                const float a = a_ch[g2 * 4 + e];
                acc0 = fmaf(sg, fabsf(a + b0[e]),  acc0);
                acc1 = fmaf(sg, fabsf(a + b1v[e]), acc1);
                acc2 = fmaf(sg, fabsf(a + b2v[e]), acc2);
            }
        }
    }

    const float base = b2[0] + rsA[b * Nc + i];
    float* orow = out + (b * Nc + i) * Nc;
    orow[j0 + lane      ] = fmaxf(base + rsB[b * Nc + j0 + lane      ] + acc0, 0.0f);
    orow[j0 + lane +  64] = fmaxf(base + rsB[b * Nc + j0 + lane +  64] + acc1, 0.0f);
    orow[j0 + lane + 128] = fmaxf(base + rsB[b * Nc + j0 + lane + 128] + acc2, 0.0f);
}

extern "C" void kernel_launch(void* const* d_in, const int* in_sizes, int n_in,
                              void* d_out, int out_size, void* d_ws, size_t ws_size,
                              hipStream_t stream) {
    const float* emb = (const float*)d_in[0];   // [B,N,D]
    const float* W1  = (const float*)d_in[1];   // [D, 2D]
    const float* b1  = (const float*)d_in[2];   // [D]
    const float* W2  = (const float*)d_in[3];   // [1, D]
    const float* b2  = (const float*)d_in[4];   // [1]
    float* out = (float*)d_out;                 // [B,N,N,1]

    float* W1p = (float*)d_ws;                  // [32][264][4]          = 33792
    float* b1p = W1p + 32 * NC2 * 4;            // [264]
    float* Avp = b1p + NC2;                     // [2880][132]           = 380160
    float* Btp = Avp + Bc * Nc * NSLOT;         // [8][33][360][4]       = 380160
    float* rsA = Btp + Bc * NG * Nc * 4;        // [2880]
    float* rsB = rsA + Bc * Nc;                 // [2880]
    int*   pmap   = (int*)(rsB + Bc * Nc);      // [132]
    int*   gsplit = pmap + NSLOT;               // [1]

    hipMemsetAsync(rsA, 0, 2 * Bc * Nc * sizeof(float), stream);
    prep_kernel<<<dim3(1), 64, 0, stream>>>(W2, pmap, gsplit);
    fillw_kernel<<<dim3(32), 256, 0, stream>>>(W1, W2, b1, pmap, W1p, b1p);
    proj_kernel<<<dim3(360, 5), 64, 0, stream>>>(emb, W1p, b1p, Avp, Btp, rsA, rsB);
    edge_kernel<<<dim3(90, 2, Bc), 256, 0, stream>>>(Avp, Btp, b2, rsA, rsB, gsplit, out);
}

// Round 9
// 52.971 us; speedup vs baseline: 1.4548x; 1.0773x over previous
//
#include <hip/hip_runtime.h>

#define Bc 8
#define Nc 360
#define Dc 128
#define NSLOT 132      // padded slots per side = 33 groups of 4
#define NG 33
#define NC2 264        // slots both sides (B-side first, then A-side)

typedef float f32x4 __attribute__((ext_vector_type(4)));

// ---------------- fillw: permutation + packed/permuted/0.5*w2-scaled W1 + b1p + rs zeroing ----
// Wave 0 of each block recomputes the sign permutation (positives of w2 first, zero-pad to
// group-of-4 boundary) into LDS; block then fills its k4 slice of W1p. Block 0 writes gsplit.
// Also zeroes rsA/rsB (contiguous 5760 floats) so proj's atomics start clean — no memset needed.
__global__ __launch_bounds__(256) void fillw_kernel(
    const float* __restrict__ W1, const float* __restrict__ W2, const float* __restrict__ b1,
    float* __restrict__ W1p, float* __restrict__ b1p, int* __restrict__ gsplit_g,
    float* __restrict__ rs)   // rs = rsA (rsB contiguous after it), 2*Bc*Nc floats
{
    __shared__ int pmap_s[NSLOT];
    const int t  = threadIdx.x;
    const int k4 = blockIdx.x;                        // 0..31

    if (t < 64) {                                     // exactly wave 0
        const int lane = t;
        pmap_s[lane] = -1; pmap_s[64 + lane] = -1;
        if (lane < 4) pmap_s[128 + lane] = -1;
        const bool p0 = W2[lane] >= 0.0f;
        const bool p1 = W2[64 + lane] >= 0.0f;
        const unsigned long long m0 = __ballot(p0);
        const unsigned long long m1 = __ballot(p1);
        const unsigned long long below = (lane == 0) ? 0ull : (~0ull >> (64 - lane));
        const int cnt = __popcll(m0) + __popcll(m1);
        const int gs  = (cnt + 3) >> 2;
        if (lane == 0 && k4 == 0) *gsplit_g = gs;
        const int pr0 = __popcll(m0 & below);
        const int pr1 = __popcll(m0) + __popcll(m1 & below);
        const int nr0 = __popcll(~m0 & below);
        const int nr1 = __popcll(~m0) + __popcll(~m1 & below);
        // same-wave LDS writes are program-ordered: clears above, ranked scatter below
        if (p0) pmap_s[pr0] = lane;      else pmap_s[gs * 4 + nr0] = lane;
        if (p1) pmap_s[pr1] = 64 + lane; else pmap_s[gs * 4 + nr1] = 64 + lane;
    }
    __syncthreads();

    for (int c = t; c < NC2; c += 256) {
        const int side = (c >= NSLOT);               // 0 = B (sender), 1 = A (receiver)
        const int cm   = side ? c - NSLOT : c;
        const int pd   = pmap_s[cm];
        f32x4 v = {0.f, 0.f, 0.f, 0.f};
        if (pd >= 0) {
            const float sc = 0.5f * W2[pd];
            const float* src = W1 + pd * (2 * Dc) + side * Dc + k4 * 4;
            v[0] = sc * src[0]; v[1] = sc * src[1]; v[2] = sc * src[2]; v[3] = sc * src[3];
        }
        *(f32x4*)(W1p + (k4 * NC2 + c) * 4) = v;
        if (k4 == 0)
            b1p[c] = (side && pd >= 0) ? 0.5f * W2[pd] * b1[pd] : 0.0f;
    }

    // zero row-sum accumulators: 32 blocks x 256 threads = 8192 >= 5760
    const int idx = k4 * 256 + t;
    if (idx < 2 * Bc * Nc) rs[idx] = 0.0f;
}

// ---------------- proj ----------------
// Avp[b*360+n][s] = A'-slot values; Btp[b][g][n][e] = B'-slot values; rs* = row sums (atomic).
// Wave: lane <-> slot column c (coalesced W1p loads); 8 rows via VMEM broadcast loads
// (base made formally divergent with mbcnt so the compiler keeps them in the pipelined global path).
__global__ __launch_bounds__(64) void proj_kernel(
    const float* __restrict__ emb, const float* __restrict__ W1p, const float* __restrict__ b1p,
    float* __restrict__ Avp, float* __restrict__ Btp,
    float* __restrict__ rsA, float* __restrict__ rsB)
{
    const int lane = threadIdx.x;
    const int r0   = blockIdx.x * 8;                 // 2880/8 = 360; 360%8==0 -> one batch per block
    const int cg   = blockIdx.y;                     // 0..4
    const int c    = cg * 64 + lane;                 // 0..319
    const int cc   = (c < NC2) ? c : (NC2 - 1);      // clamp for loads
    const int dz   = __builtin_amdgcn_mbcnt_lo(0u, 0u);  // == 0, divergent-typed

    float acc[8];
    const float binit = b1p[cc];
    #pragma unroll
    for (int r = 0; r < 8; ++r) acc[r] = binit;

    const float* wp = W1p + cc * 4;
    const float* ep = emb + (r0 + dz) * Dc;          // divergent base -> VMEM broadcast loads

    #pragma unroll 4
    for (int k4 = 0; k4 < 32; ++k4) {
        const f32x4 wv = *(const f32x4*)(wp + k4 * NC2 * 4);   // coalesced b128
        #pragma unroll
        for (int r = 0; r < 8; ++r) {
            const f32x4 ev = *(const f32x4*)(ep + r * Dc + k4 * 4);  // broadcast (1 line)
            acc[r] = fmaf(wv[0], ev[0], acc[r]);
            acc[r] = fmaf(wv[1], ev[1], acc[r]);
            acc[r] = fmaf(wv[2], ev[2], acc[r]);
            acc[r] = fmaf(wv[3], ev[3], acc[r]);
        }
    }

    const bool valid = (c < NC2);
    const int  side  = (c >= NSLOT);                 // per-lane
    const int  cm    = side ? c - NSLOT : c;
    const int  bidx  = r0 / Nc;                      // uniform
    const int  nb    = r0 - bidx * Nc;

    #pragma unroll
    for (int r = 0; r < 8; ++r) {
        const int n = nb + r;
        if (valid) {
            if (side) Avp[(bidx * Nc + n) * NSLOT + cm] = acc[r];                       // contiguous
            else      Btp[((bidx * NG + (cm >> 2)) * Nc + n) * 4 + (cm & 3)] = acc[r];  // 16B segs
        }
        float vA = (valid && side)  ? acc[r] : 0.0f;
        float vB = (valid && !side) ? acc[r] : 0.0f;
        #pragma unroll
        for (int m = 32; m >= 1; m >>= 1) { vA += __shfl_xor(vA, m); vB += __shfl_xor(vB, m); }
        if (lane == 0) {
            if (cg >= 2) atomicAdd(rsA + bidx * Nc + n, vA);
            if (cg <= 2) atomicAdd(rsB + bidx * Nc + n, vB);
        }
    }
}

// ---------------- edge ----------------
// out[b,i,j] = relu( b2 + rsA[i] + rsB[j] + sum_g sgn_g * sum_e |a[g,e] + b[j,g,e]| )
// Block = 4 waves; wave = 1 i-row x 192 j (3 per lane). Grid (90, 2, 8) = 1440 blocks.
// a-row in SGPRs (chunked preload, static indices); B per-lane coalesced b128 from Btp.
__global__ __launch_bounds__(256) void edge_kernel(
    const float* __restrict__ Avp, const float* __restrict__ Btp,
    const float* __restrict__ b2, const float* __restrict__ rsA,
    const float* __restrict__ rsB, const int* __restrict__ gsplit_p,
    float* __restrict__ out)
{
    const int t    = threadIdx.x;
    const int lane = t & 63;
    const int wid  = __builtin_amdgcn_readfirstlane(t >> 6);
    const int b    = blockIdx.z;
    const int i    = blockIdx.x * 4 + wid;           // uniform per wave
    const int j0   = blockIdx.y * 168;               // halves [0,192) and [168,360): overlap idempotent
    const int gsplit = *gsplit_p;                    // uniform

    const float* arow = Avp + (b * Nc + i) * NSLOT;  // uniform -> s_load
    const float* bp   = Btp + (b * NG * Nc + j0 + lane) * 4;   // per-lane; + g*Nc*4 per group

    float acc0 = 0.0f, acc1 = 0.0f, acc2 = 0.0f;

    #pragma unroll
    for (int ch = 0; ch < 3; ++ch) {
        float a_ch[44];
        #pragma unroll
        for (int s = 0; s < 44; ++s) a_ch[s] = arow[ch * 44 + s];   // uniform -> SGPRs
        #pragma unroll
        for (int g2 = 0; g2 < 11; ++g2) {
            const int g = ch * 11 + g2;
            const float sg = (g < gsplit) ? 1.0f : -1.0f;            // uniform select
            const f32x4 b0 = *(const f32x4*)(bp + (g * Nc +   0) * 4);
            const f32x4 b1v = *(const f32x4*)(bp + (g * Nc +  64) * 4);
            const f32x4 b2v = *(const f32x4*)(bp + (g * Nc + 128) * 4);
            #pragma unroll
            for (int e = 0; e < 4; ++e) {
                const float a = a_ch[g2 * 4 + e];
                acc0 = fmaf(sg, fabsf(a + b0[e]),  acc0);
                acc1 = fmaf(sg, fabsf(a + b1v[e]), acc1);
                acc2 = fmaf(sg, fabsf(a + b2v[e]), acc2);
            }
        }
    }

    const float base = b2[0] + rsA[b * Nc + i];
    float* orow = out + (b * Nc + i) * Nc;
    orow[j0 + lane      ] = fmaxf(base + rsB[b * Nc + j0 + lane      ] + acc0, 0.0f);
    orow[j0 + lane +  64] = fmaxf(base + rsB[b * Nc + j0 + lane +  64] + acc1, 0.0f);
    orow[j0 + lane + 128] = fmaxf(base + rsB[b * Nc + j0 + lane + 128] + acc2, 0.0f);
}

extern "C" void kernel_launch(void* const* d_in, const int* in_sizes, int n_in,
                              void* d_out, int out_size, void* d_ws, size_t ws_size,
                              hipStream_t stream) {
    const float* emb = (const float*)d_in[0];   // [B,N,D]
    const float* W1  = (const float*)d_in[1];   // [D, 2D]
    const float* b1  = (const float*)d_in[2];   // [D]
    const float* W2  = (const float*)d_in[3];   // [1, D]
    const float* b2  = (const float*)d_in[4];   // [1]
    float* out = (float*)d_out;                 // [B,N,N,1]

    float* W1p = (float*)d_ws;                  // [32][264][4]          = 33792
    float* b1p = W1p + 32 * NC2 * 4;            // [264]
    float* Avp = b1p + NC2;                     // [2880][132]           = 380160
    float* Btp = Avp + Bc * Nc * NSLOT;         // [8][33][360][4]       = 380160
    float* rsA = Btp + Bc * NG * Nc * 4;        // [2880]
    float* rsB = rsA + Bc * Nc;                 // [2880]  (contiguous after rsA)
    int*   gsplit = (int*)(rsB + Bc * Nc);      // [1]

    fillw_kernel<<<dim3(32), 256, 0, stream>>>(W1, W2, b1, W1p, b1p, gsplit, rsA);
    proj_kernel<<<dim3(360, 5), 64, 0, stream>>>(emb, W1p, b1p, Avp, Btp, rsA, rsB);
    edge_kernel<<<dim3(90, 2, Bc), 256, 0, stream>>>(Avp, Btp, b2, rsA, rsB, gsplit, out);
}